// Round 4
// baseline (360.749 us; speedup 1.0000x reference)
//
#include <hip/hip_runtime.h>

// Problem constants: B=4, S=2048 -> T=8192 tokens; H=512, F=2048, E=8, K=2.
#define T_TOKENS 8192
#define HD 512
#define FD 2048
#define NE 8
#define CAP 8192   // per-expert bucket capacity (worst case all tokens -> one expert)
#define CSTRIDE 32 // counter padding: 32 ints = 128B, one counter per cache line

typedef __attribute__((ext_vector_type(8))) short short8;   // 8 bf16 = 4 VGPRs
typedef __attribute__((ext_vector_type(4))) float f32x4;    // MFMA accumulator

__device__ __forceinline__ ushort f2bf(float f) {
  union { float f; unsigned u; } v; v.f = f;
  unsigned u = v.u;
  return (ushort)((u + 0x7fffu + ((u >> 16) & 1u)) >> 16);  // RNE
}

// async global->LDS, 16B per lane. LDS dest is wave-uniform base + lane*16.
__device__ __forceinline__ void gld16(const ushort* g, ushort* l) {
  __builtin_amdgcn_global_load_lds(
      (const __attribute__((address_space(1))) void*)g,
      (__attribute__((address_space(3))) void*)l, 16, 0, 0);
}

// ---------------- fp32 -> bf16 bulk convert ----------------
__global__ void cvt_bf16(const float4* __restrict__ src, ushort4* __restrict__ dst, int n4) {
  int i = blockIdx.x * blockDim.x + threadIdx.x;
  int st = gridDim.x * blockDim.x;
  for (; i < n4; i += st) {
    float4 v = src[i];
    ushort4 o;
    o.x = f2bf(v.x); o.y = f2bf(v.y); o.z = f2bf(v.z); o.w = f2bf(v.w);
    dst[i] = o;
  }
}

// ---------------- router: logits -> softmax -> top2 -> buckets ----------------
#define TPW 16
__global__ void router_kernel(const float* __restrict__ x, const float* __restrict__ rw,
                              float* __restrict__ probs_out, float* __restrict__ topk_out,
                              int* __restrict__ counts, int* __restrict__ bucket_tok,
                              float* __restrict__ bucket_w, int4* __restrict__ tok_info) {
  __shared__ int lcnt[NE];
  __shared__ int lbase[NE];
  __shared__ int ls_e0[64], ls_e1[64], ls_s0[64], ls_s1[64];
  __shared__ float ls_w0[64], ls_w1[64];

  int wave = threadIdx.x >> 6, lane = threadIdx.x & 63;
  if (threadIdx.x < NE) lcnt[threadIdx.x] = 0;
  __syncthreads();

  int tbase = blockIdx.x * 64;
  for (int it = 0; it < TPW; it++) {
    int lt = wave * TPW + it;
    int t = tbase + lt;
    float acc[NE];
#pragma unroll
    for (int e = 0; e < NE; e++) acc[e] = 0.f;
    const float* xr = x + (size_t)t * HD;
    for (int c = 0; c < HD; c += 64) {
      float xv = xr[c + lane];
#pragma unroll
      for (int e = 0; e < NE; e++) acc[e] += xv * rw[e * HD + c + lane];
    }
#pragma unroll
    for (int e = 0; e < NE; e++) {
#pragma unroll
      for (int s = 32; s > 0; s >>= 1) acc[e] += __shfl_xor(acc[e], s, 64);
    }
    if (lane == 0) {
      float m = acc[0];
#pragma unroll
      for (int e = 1; e < NE; e++) m = fmaxf(m, acc[e]);
      float p[NE], s = 0.f;
#pragma unroll
      for (int e = 0; e < NE; e++) { p[e] = expf(acc[e] - m); s += p[e]; }
      float inv = 1.f / s;
#pragma unroll
      for (int e = 0; e < NE; e++) { p[e] *= inv; probs_out[(size_t)t * NE + e] = p[e]; }
      int i0 = 0;
#pragma unroll
      for (int e = 1; e < NE; e++) if (p[e] > p[i0]) i0 = e;
      int i1 = (i0 == 0) ? 1 : 0;
#pragma unroll
      for (int e = 0; e < NE; e++) if (e != i0 && p[e] > p[i1]) i1 = e;
      float r = 1.f / (p[i0] + p[i1] + 1e-9f);
      topk_out[(size_t)t * 2 + 0] = (float)i0;
      topk_out[(size_t)t * 2 + 1] = (float)i1;
      ls_e0[lt] = i0; ls_e1[lt] = i1;
      ls_w0[lt] = p[i0] * r; ls_w1[lt] = p[i1] * r;
      ls_s0[lt] = atomicAdd(&lcnt[i0], 1);
      ls_s1[lt] = atomicAdd(&lcnt[i1], 1);
    }
  }
  __syncthreads();
  if (threadIdx.x < NE)
    lbase[threadIdx.x] = atomicAdd(&counts[threadIdx.x * CSTRIDE], lcnt[threadIdx.x]);
  __syncthreads();
  if (threadIdx.x < 64) {
    int lt = threadIdx.x, t = tbase + lt;
    int e0 = ls_e0[lt], e1 = ls_e1[lt];
    int g0 = lbase[e0] + ls_s0[lt];
    int g1 = lbase[e1] + ls_s1[lt];
    bucket_tok[e0 * CAP + g0] = t; bucket_w[e0 * CAP + g0] = ls_w0[lt];
    bucket_tok[e1 * CAP + g1] = t; bucket_w[e1 * CAP + g1] = ls_w1[lt];
    tok_info[t] = make_int4(e0, e1, g0, g1);
  }
}

__global__ void scan_kernel(const int* __restrict__ counts, int* __restrict__ offsets) {
  if (threadIdx.x == 0) {
    int o = 0;
#pragma unroll
    for (int e = 0; e < NE; e++) { offsets[e] = o; o += counts[e * CSTRIDE]; }
  }
}

// ---------------- 8-phase grouped GEMM (256-row tile, BK=64) ----------------
// T2: 3-bit row-XOR swizzle (byte ^= (row&7)<<4): spreads the 16-lane
//     stride-128B ds_read_b128 groups across all 8 16B bank-groups ->
//     uniform 8 lanes/bank-group = bandwidth floor, no conflict serialization.
//     Applied as linear gld_lds dest + inverse-swizzled GLOBAL source column +
//     swizzled ds_read (both-sides-or-neither, rule #21).
// T3+T4: 8 phases / 2 K-tiles per iteration; race-free 2-buffer schedule:
//     stage full tile t+1 at the FIRST phase after its buffer's readers
//     finish (phase 1 / phase 5), counted-or-zero vmcnt only at phases 4/8.
//     Prologue pre-stages tiles 0 AND 1 with a counted vmcnt(NL) so tile 1
//     stays in flight across the whole first half-iteration (peeled iter 0).
// T5: s_setprio(1) around each MFMA cluster.

// swizzled LDS fragment read: row-major [rows][64] bf16 tile
__device__ __forceinline__ short8 ldsr(const ushort* base, int row, int ks, int q) {
  int a = row * 128 + ks * 64 + q * 16;
  a ^= (row & 7) << 4;   // 3-bit row swizzle, bijective within the 128B row
  return *(const short8*)((const char*)base + a);
}

#define VM0 asm volatile("s_waitcnt vmcnt(0)" ::: "memory")
#define VMC(N) asm volatile("s_waitcnt vmcnt(" #N ")" ::: "memory")
#define SB0 __builtin_amdgcn_sched_barrier(0)

// stage one full K-tile (A: 4 units of 64 rows; B: 2*LB units) into buffer (KT_&1)
#define STG_TILE(KT_) do { \
    ushort* _la = ldsA + (((KT_) & 1) ? AT : 0) + tid * 8; \
    ushort* _lb = ldsB + (((KT_) & 1) ? BT : 0) + tid * 8; \
    gld16(aS[0][0] + (KT_) * 64, _la); \
    gld16(aS[0][1] + (KT_) * 64, _la + 4096); \
    gld16(aS[1][0] + (KT_) * 64, _la + 8192); \
    gld16(aS[1][1] + (KT_) * 64, _la + 12288); \
    gld16(bS[0][0] + (KT_) * 64, _lb); \
    if (LB == 2) gld16(bS[0][1] + (KT_) * 64, _lb + 4096); \
    gld16(bS[1][0] + (KT_) * 64, _lb + BH); \
    if (LB == 2) gld16(bS[1][1] + (KT_) * 64, _lb + BH + 4096); \
  } while (0)

#define PHASE(PA, PB, QI, QJ, STG, VMW) do { \
    if ((QJ) == 0) { \
      _Pragma("unroll") for (int mm = 0; mm < MFR_H; ++mm) { \
        af[mm][0] = ldsr((PA), wrowA + ((QI) * MFR_H + mm) * 16, 0, q); \
        af[mm][1] = ldsr((PA), wrowA + ((QI) * MFR_H + mm) * 16, 1, q); \
      } \
    } \
    if ((QI) == 0) { \
      _Pragma("unroll") for (int nn = 0; nn < 2; ++nn) { \
        bf[(QJ) * 2 + nn][0] = ldsr((PB), wrowB + ((QJ) * 2 + nn) * 16, 0, q); \
        bf[(QJ) * 2 + nn][1] = ldsr((PB), wrowB + ((QJ) * 2 + nn) * 16, 1, q); \
      } \
    } \
    STG; \
    SB0; \
    __builtin_amdgcn_s_barrier(); \
    asm volatile("s_waitcnt lgkmcnt(0)" ::: "memory"); \
    SB0; \
    __builtin_amdgcn_s_setprio(1); \
    _Pragma("unroll") for (int mm = 0; mm < MFR_H; ++mm) \
      _Pragma("unroll") for (int nn = 0; nn < 2; ++nn) { \
        acc[(QI) * MFR_H + mm][(QJ) * 2 + nn] = __builtin_amdgcn_mfma_f32_16x16x32_bf16( \
            af[mm][0], bf[(QJ) * 2 + nn][0], acc[(QI) * MFR_H + mm][(QJ) * 2 + nn], 0, 0, 0); \
        acc[(QI) * MFR_H + mm][(QJ) * 2 + nn] = __builtin_amdgcn_mfma_f32_16x16x32_bf16( \
            af[mm][1], bf[(QJ) * 2 + nn][1], acc[(QI) * MFR_H + mm][(QJ) * 2 + nn], 0, 0, 0); \
      } \
    __builtin_amdgcn_s_setprio(0); \
    VMW; \
    SB0; \
    __builtin_amdgcn_s_barrier(); \
  } while (0)

template <bool IS_FC1, int BN_, int WM_, int WN_, int KD_, int ND_>
__global__ __launch_bounds__(512, 2)
void ffn_gemm8(const ushort* __restrict__ Ab, const ushort* __restrict__ Bw,
               const float* __restrict__ bias, const int* __restrict__ counts,
               const int* __restrict__ offsets, const int* __restrict__ bucket_tok,
               const float* __restrict__ bucket_w, ushort* __restrict__ Aout,
               float* __restrict__ Yout) {
  constexpr int BM = 256;
  constexpr int MFR = BM / WM_ / 16;      // 8 (FC1) or 4 (FC2) m-frags per wave
  constexpr int NFR = BN_ / WN_ / 16;     // 4 in both configs
  constexpr int MFR_H = MFR / 2;
  constexpr int LB = BN_ / 128;           // gld16 units per B half
  constexpr int AT = BM * 64;             // ushorts per A tile (one db)
  constexpr int BT = BN_ * 64;
  constexpr int BH = (BN_ / 2) * 64;      // ushorts per B half
  constexpr int KT = KD_ / 64;
  constexpr int NIT = KT / 2;
  static_assert(NFR == 4, "phase structure assumes 4 n-frags per wave");
  static_assert((KT & 1) == 0 && NIT >= 3, "schedule needs even KT, NIT>=3");

  int e = blockIdx.z;
  int cnt = counts[e * CSTRIDE];
  int m0 = blockIdx.y * BM;
  if (m0 >= cnt) return;
  int n0 = blockIdx.x * BN_;
  int off = offsets[e];

  extern __shared__ ushort smem[];
  ushort* ldsA = smem;            // [2][256][64]
  ushort* ldsB = smem + 2 * AT;   // [2][BN][64]

  int tid = threadIdx.x;
  int lid = tid & 63, w = tid >> 6;
  int wm = w / WN_, wn = w % WN_;
  int q = lid >> 4, l16 = lid & 15;
  int r0 = tid >> 3;  // staging dest row within a 64-row unit (8 lanes/row)
  // inverse-swizzled source column (ushorts): ((tid&7)*8) ^ ((r0&7)*8).
  // Every staging unit's dest-row base is a multiple of 64, so row&7 == r0&7
  // for all units -> one colElem serves all 8 gld16s.
  int colElem = (((tid & 7) ^ ((tid >> 3) & 7)) << 3);

  const ushort *aS[2][2], *bS[2][2];  // [half][unit] source row pointers
#pragma unroll
  for (int h = 0; h < 2; ++h)
#pragma unroll
    for (int c = 0; c < 2; ++c) {
      int rA = min(m0 + h * 128 + r0 + c * 64, cnt - 1);
      int tok = IS_FC1 ? bucket_tok[e * CAP + rA] : (off + rA);
      aS[h][c] = Ab + (size_t)tok * KD_ + colElem;
      int rB = n0 + h * (BN_ / 2) + min(r0 + c * 64, BN_ / 2 - 1);
      bS[h][c] = Bw + ((size_t)e * ND_ + rB) * KD_ + colElem;
    }

  f32x4 acc[MFR][NFR] = {};
  short8 af[MFR_H][2], bf[4][2];

  int wrowA = wm * (BM / WM_) + l16;
  int wrowB = wn * (BN_ / WN_) + l16;
  const ushort* pA0 = ldsA;
  const ushort* pB0 = ldsB;
  const ushort* pA1 = ldsA + AT;
  const ushort* pB1 = ldsB + BT;

  // prologue: stage tiles 0 AND 1 (buf0, buf1 both idle); counted wait keeps
  // tile 1's loads in flight while tile 0 becomes resident.
  STG_TILE(0);
  STG_TILE(1);
  if constexpr (LB == 2) VMC(8); else VMC(6);   // oldest NL (= tile 0) retired
  SB0;
  __builtin_amdgcn_s_barrier();

  // peeled iteration 0: tile 1 already staged; phase-4 VM0 is a no-stall drain
  PHASE(pA0, pB0, 0, 0, (void)0, (void)0);
  PHASE(pA0, pB0, 0, 1, (void)0, (void)0);
  PHASE(pA0, pB0, 1, 0, (void)0, (void)0);
  PHASE(pA0, pB0, 1, 1, (void)0, VM0);          // tile 1 resident (prologue)
  PHASE(pA1, pB1, 0, 0, STG_TILE(2), (void)0);
  PHASE(pA1, pB1, 0, 1, (void)0, (void)0);
  PHASE(pA1, pB1, 1, 0, (void)0, (void)0);
  PHASE(pA1, pB1, 1, 1, (void)0, VM0);          // tile 2 resident

  for (int it = 1; it < NIT - 1; ++it) {
    // phases 1-4: compute tile 2it (buf0); phase 1 stages tile 2it+1 -> buf1
    PHASE(pA0, pB0, 0, 0, STG_TILE(2 * it + 1), (void)0);
    PHASE(pA0, pB0, 0, 1, (void)0, (void)0);
    PHASE(pA0, pB0, 1, 0, (void)0, (void)0);
    PHASE(pA0, pB0, 1, 1, (void)0, VM0);        // tile 2it+1 resident
    // phases 5-8: compute tile 2it+1 (buf1); phase 5 stages tile 2it+2 -> buf0
    PHASE(pA1, pB1, 0, 0, STG_TILE(2 * it + 2), (void)0);
    PHASE(pA1, pB1, 0, 1, (void)0, (void)0);
    PHASE(pA1, pB1, 1, 0, (void)0, (void)0);
    PHASE(pA1, pB1, 1, 1, (void)0, VM0);        // tile 2it+2 resident
  }
  // tail iteration: compute KT-2 (buf0) staging KT-1 -> buf1, then compute KT-1
  PHASE(pA0, pB0, 0, 0, STG_TILE(KT - 1), (void)0);
  PHASE(pA0, pB0, 0, 1, (void)0, (void)0);
  PHASE(pA0, pB0, 1, 0, (void)0, (void)0);
  PHASE(pA0, pB0, 1, 1, (void)0, VM0);
  PHASE(pA1, pB1, 0, 0, (void)0, (void)0);
  PHASE(pA1, pB1, 0, 1, (void)0, (void)0);
  PHASE(pA1, pB1, 1, 0, (void)0, (void)0);
  PHASE(pA1, pB1, 1, 1, (void)0, (void)0);

  // ---- epilogue via LDS round-trip for 16B contiguous global stores ----
  float bcol[NFR];
#pragma unroll
  for (int n = 0; n < NFR; ++n)
    bcol[n] = bias[(size_t)e * ND_ + n0 + wn * (BN_ / WN_) + n * 16 + l16];

  if constexpr (IS_FC1) {
    // stage WM*16=32 rows x 256 cols bf16 per m-round; row stride 264 (528B, 16B-aligned)
    ushort* Ct = smem;
#pragma unroll
    for (int m = 0; m < MFR; ++m) {
      __syncthreads();
#pragma unroll
      for (int n = 0; n < NFR; ++n)
#pragma unroll
        for (int r = 0; r < 4; ++r) {
          float v = acc[m][n][r] + bcol[n];
          float g = 0.5f * v * (1.0f + erff(v * 0.70710678118654752f));
          Ct[(wm * 16 + q * 4 + r) * 264 + wn * (BN_ / WN_) + n * 16 + l16] = f2bf(g);
        }
      __syncthreads();
#pragma unroll
      for (int u = 0; u < 2; ++u) {
        int c = tid + u * 512;          // 1024 chunks of 8 bf16
        int rl = c >> 5, cc = c & 31;
        int gm = m0 + (rl >> 4) * (BM / WM_) + m * 16 + (rl & 15);
        if (gm < cnt)
          *(uint4*)&Aout[(size_t)(off + gm) * ND_ + n0 + cc * 8] =
              *(const uint4*)&Ct[rl * 264 + cc * 8];
      }
    }
  } else {
    // stage WM*16=64 rows x 128 cols fp32 per m-round; row stride 132 (528B)
    float* Cf = (float*)smem;
#pragma unroll
    for (int m = 0; m < MFR; ++m) {
      __syncthreads();
#pragma unroll
      for (int r = 0; r < 4; ++r) {
        int gm = m0 + wm * (BM / WM_) + m * 16 + q * 4 + r;
        float wgt = bucket_w[e * CAP + min(gm, cnt - 1)];
#pragma unroll
        for (int n = 0; n < NFR; ++n)
          Cf[(wm * 16 + q * 4 + r) * 132 + wn * (BN_ / WN_) + n * 16 + l16] =
              wgt * (acc[m][n][r] + bcol[n]);
      }
      __syncthreads();
#pragma unroll
      for (int u = 0; u < 4; ++u) {
        int c = tid + u * 512;          // 2048 chunks of 4 floats
        int rl = c >> 5, cc = c & 31;
        int gm = m0 + (rl >> 4) * (BM / WM_) + m * 16 + (rl & 15);
        if (gm < cnt)
          *(float4*)&Yout[(size_t)(off + gm) * ND_ + n0 + cc * 4] =
              *(const float4*)&Cf[rl * 132 + cc * 4];
      }
    }
  }
}

// ---------------- combine: out[t] = Y[row(e0,s0)] + Y[row(e1,s1)] ----------------
__global__ void combine_kernel(const float4* __restrict__ Y, const int4* __restrict__ tok_info,
                               const int* __restrict__ offsets, float4* __restrict__ out) {
  int t = blockIdx.x;
  int4 ti = tok_info[t];
  int g0 = offsets[ti.x] + ti.z;
  int g1 = offsets[ti.y] + ti.w;
  int i = threadIdx.x;  // 128 threads, H/4 = 128 float4 per row
  float4 a = Y[(size_t)g0 * (HD / 4) + i];
  float4 b = Y[(size_t)g1 * (HD / 4) + i];
  out[(size_t)t * (HD / 4) + i] = make_float4(a.x + b.x, a.y + b.y, a.z + b.z, a.w + b.w);
}

extern "C" void kernel_launch(void* const* d_in, const int* in_sizes, int n_in,
                              void* d_out, int out_size, void* d_ws, size_t ws_size,
                              hipStream_t stream) {
  const float* x    = (const float*)d_in[0];
  const float* rw   = (const float*)d_in[1];
  const float* fc1w = (const float*)d_in[2];
  const float* fc1b = (const float*)d_in[3];
  const float* fc2w = (const float*)d_in[4];
  const float* fc2b = (const float*)d_in[5];

  float* out   = (float*)d_out;
  float* probs = out + (size_t)T_TOKENS * HD;
  float* topk  = probs + (size_t)T_TOKENS * NE;

  // Defensive: allow >64 KiB dynamic LDS (host-side attribute, graph-capture safe).
  static bool attr_done = false;
  if (!attr_done) {
    (void)hipFuncSetAttribute((const void*)&ffn_gemm8<true, 256, 2, 4, HD, FD>,
                              hipFuncAttributeMaxDynamicSharedMemorySize, 131072);
    (void)hipFuncSetAttribute((const void*)&ffn_gemm8<false, 128, 4, 2, FD, HD>,
                              hipFuncAttributeMaxDynamicSharedMemorySize, 98304);
    attr_done = true;
  }

  char* p = (char*)d_ws;
  auto carve = [&](size_t bytes) { char* r = p; p += (bytes + 255) & ~(size_t)255; return r; };
  int*    counts     = (int*)carve(NE * CSTRIDE * sizeof(int));
  int*    offsets    = (int*)carve(NE * sizeof(int));
  int*    bucket_tok = (int*)carve((size_t)NE * CAP * sizeof(int));
  float*  bucket_w   = (float*)carve((size_t)NE * CAP * sizeof(float));
  int4*   tok_info   = (int4*)carve((size_t)T_TOKENS * sizeof(int4));
  ushort* xb   = (ushort*)carve((size_t)T_TOKENS * HD * 2);
  ushort* w1b  = (ushort*)carve((size_t)NE * FD * HD * 2);
  ushort* w2b  = (ushort*)carve((size_t)NE * HD * FD * 2);
  ushort* Abuf = (ushort*)carve((size_t)T_TOKENS * 2 * FD * 2);  // compact GELU out, bf16
  float*  Y    = (float*)carve((size_t)T_TOKENS * 2 * HD * 4);   // gated FC2 rows, fp32

  hipMemsetAsync(counts, 0, NE * CSTRIDE * sizeof(int), stream);
  cvt_bf16<<<2048, 256, 0, stream>>>((const float4*)x, (ushort4*)xb, T_TOKENS * HD / 4);
  cvt_bf16<<<2048, 256, 0, stream>>>((const float4*)fc1w, (ushort4*)w1b, NE * FD * HD / 4);
  cvt_bf16<<<2048, 256, 0, stream>>>((const float4*)fc2w, (ushort4*)w2b, NE * HD * FD / 4);
  router_kernel<<<T_TOKENS / 64, 256, 0, stream>>>(x, rw, probs, topk, counts, bucket_tok,
                                                   bucket_w, tok_info);
  scan_kernel<<<1, 64, 0, stream>>>(counts, offsets);

  // FC1: 256x256 tile, 2x4 waves, K=512; LDS = 2*(256+256)*64*2 = 128 KiB
  ffn_gemm8<true, 256, 2, 4, HD, FD>
      <<<dim3(FD / 256, CAP / 256, NE), 512, 131072, stream>>>(
          xb, w1b, fc1b, counts, offsets, bucket_tok, bucket_w, Abuf, nullptr);
  // FC2: 256x128 tile, 4x2 waves, K=2048; LDS = 2*(256+128)*64*2 = 96 KiB
  ffn_gemm8<false, 128, 4, 2, FD, HD>
      <<<dim3(HD / 128, CAP / 256, NE), 512, 98304, stream>>>(
          Abuf, w2b, fc2b, counts, offsets, bucket_tok, bucket_w, nullptr, Y);

  combine_kernel<<<T_TOKENS, 128, 0, stream>>>((const float4*)Y, tok_info, offsets, (float4*)out);
}

// Round 5
// 334.239 us; speedup vs baseline: 1.0793x; 1.0793x over previous
//
#include <hip/hip_runtime.h>

// Problem constants: B=4, S=2048 -> T=8192 tokens; H=512, F=2048, E=8, K=2.
#define T_TOKENS 8192
#define HD 512
#define FD 2048
#define NE 8
#define CAP 8192   // per-expert bucket capacity (worst case all tokens -> one expert)
#define CSTRIDE 32 // counter padding: 32 ints = 128B, one counter per cache line

typedef __attribute__((ext_vector_type(8))) short short8;   // 8 bf16 = 4 VGPRs
typedef __attribute__((ext_vector_type(4))) float f32x4;    // MFMA accumulator

__device__ __forceinline__ ushort f2bf(float f) {
  union { float f; unsigned u; } v; v.f = f;
  unsigned u = v.u;
  return (ushort)((u + 0x7fffu + ((u >> 16) & 1u)) >> 16);  // RNE
}

// async global->LDS, 16B per lane. LDS dest is wave-uniform base + lane*16.
__device__ __forceinline__ void gld16(const ushort* g, ushort* l) {
  __builtin_amdgcn_global_load_lds(
      (const __attribute__((address_space(1))) void*)g,
      (__attribute__((address_space(3))) void*)l, 16, 0, 0);
}

// ---------------- fp32 -> bf16 bulk convert ----------------
__global__ void cvt_bf16(const float4* __restrict__ src, ushort4* __restrict__ dst, int n4) {
  int i = blockIdx.x * blockDim.x + threadIdx.x;
  int st = gridDim.x * blockDim.x;
  for (; i < n4; i += st) {
    float4 v = src[i];
    ushort4 o;
    o.x = f2bf(v.x); o.y = f2bf(v.y); o.z = f2bf(v.z); o.w = f2bf(v.w);
    dst[i] = o;
  }
}

// ---------------- router: logits -> softmax -> top2 -> buckets ----------------
#define TPW 16
__global__ void router_kernel(const float* __restrict__ x, const float* __restrict__ rw,
                              float* __restrict__ probs_out, float* __restrict__ topk_out,
                              int* __restrict__ counts, int* __restrict__ bucket_tok,
                              float* __restrict__ bucket_w, int4* __restrict__ tok_info) {
  __shared__ int lcnt[NE];
  __shared__ int lbase[NE];
  __shared__ int ls_e0[64], ls_e1[64], ls_s0[64], ls_s1[64];
  __shared__ float ls_w0[64], ls_w1[64];

  int wave = threadIdx.x >> 6, lane = threadIdx.x & 63;
  if (threadIdx.x < NE) lcnt[threadIdx.x] = 0;
  __syncthreads();

  int tbase = blockIdx.x * 64;
  for (int it = 0; it < TPW; it++) {
    int lt = wave * TPW + it;
    int t = tbase + lt;
    float acc[NE];
#pragma unroll
    for (int e = 0; e < NE; e++) acc[e] = 0.f;
    const float* xr = x + (size_t)t * HD;
    for (int c = 0; c < HD; c += 64) {
      float xv = xr[c + lane];
#pragma unroll
      for (int e = 0; e < NE; e++) acc[e] += xv * rw[e * HD + c + lane];
    }
#pragma unroll
    for (int e = 0; e < NE; e++) {
#pragma unroll
      for (int s = 32; s > 0; s >>= 1) acc[e] += __shfl_xor(acc[e], s, 64);
    }
    if (lane == 0) {
      float m = acc[0];
#pragma unroll
      for (int e = 1; e < NE; e++) m = fmaxf(m, acc[e]);
      float p[NE], s = 0.f;
#pragma unroll
      for (int e = 0; e < NE; e++) { p[e] = expf(acc[e] - m); s += p[e]; }
      float inv = 1.f / s;
#pragma unroll
      for (int e = 0; e < NE; e++) { p[e] *= inv; probs_out[(size_t)t * NE + e] = p[e]; }
      int i0 = 0;
#pragma unroll
      for (int e = 1; e < NE; e++) if (p[e] > p[i0]) i0 = e;
      int i1 = (i0 == 0) ? 1 : 0;
#pragma unroll
      for (int e = 0; e < NE; e++) if (e != i0 && p[e] > p[i1]) i1 = e;
      float r = 1.f / (p[i0] + p[i1] + 1e-9f);
      topk_out[(size_t)t * 2 + 0] = (float)i0;
      topk_out[(size_t)t * 2 + 1] = (float)i1;
      ls_e0[lt] = i0; ls_e1[lt] = i1;
      ls_w0[lt] = p[i0] * r; ls_w1[lt] = p[i1] * r;
      ls_s0[lt] = atomicAdd(&lcnt[i0], 1);
      ls_s1[lt] = atomicAdd(&lcnt[i1], 1);
    }
  }
  __syncthreads();
  if (threadIdx.x < NE)
    lbase[threadIdx.x] = atomicAdd(&counts[threadIdx.x * CSTRIDE], lcnt[threadIdx.x]);
  __syncthreads();
  if (threadIdx.x < 64) {
    int lt = threadIdx.x, t = tbase + lt;
    int e0 = ls_e0[lt], e1 = ls_e1[lt];
    int g0 = lbase[e0] + ls_s0[lt];
    int g1 = lbase[e1] + ls_s1[lt];
    bucket_tok[e0 * CAP + g0] = t; bucket_w[e0 * CAP + g0] = ls_w0[lt];
    bucket_tok[e1 * CAP + g1] = t; bucket_w[e1 * CAP + g1] = ls_w1[lt];
    tok_info[t] = make_int4(e0, e1, g0, g1);
  }
}

__global__ void scan_kernel(const int* __restrict__ counts, int* __restrict__ offsets) {
  if (threadIdx.x == 0) {
    int o = 0;
#pragma unroll
    for (int e = 0; e < NE; e++) { offsets[e] = o; o += counts[e * CSTRIDE]; }
  }
}

// ---------------- double-buffered grouped GEMM (128x128 tile, BK=64) ----------
// T3-minimum schedule (catalog recipe, m230=682TF class): per K-step
//   STAGE(buf^1, k+1); ds_read frags from buf (swizzled); MFMA; __syncthreads.
// One barrier per K-step; the barrier's implicit vmcnt(0) drains loads issued
// a full K-step (~700cy of compute) earlier. Race-free: stage targets the
// buffer whose readers finished before the PREVIOUS barrier.
// Swizzle (HW-verified this session: passed + SQ_LDS_BANK_CONFLICT=0):
//   read byte ^= (row&7)<<4 ; staging keeps LDS dest linear and permutes the
//   GLOBAL source column: colElem = ((tid&7) ^ ((tid>>3)&7)) * 8 ushorts.
// 64 KiB LDS -> 2 independent blocks/CU (no cross-block lockstep).

__device__ __forceinline__ short8 ldsr(const ushort* base, int row, int ks, int q) {
  int a = row * 128 + ks * 64 + q * 16;
  a ^= (row & 7) << 4;   // 3-bit row swizzle, bijective within the 128B row
  return *(const short8*)((const char*)base + a);
}

template <bool IS_FC1>
__global__ __launch_bounds__(256, 2)
void ffn_gemm_db(const ushort* __restrict__ Ab, const ushort* __restrict__ Bw,
                 const float* __restrict__ bias, const int* __restrict__ counts,
                 const int* __restrict__ offsets, const int* __restrict__ bucket_tok,
                 const float* __restrict__ bucket_w, ushort* __restrict__ Aout,
                 float* __restrict__ Yout, int KD, int ND) {
  constexpr int ATILE = 128 * 64;  // ushorts per tile buffer (16 KB)

  int e = blockIdx.z;
  int cnt = counts[e * CSTRIDE];
  int m0 = blockIdx.y * 128;
  if (m0 >= cnt) return;
  int n0 = blockIdx.x * 128;
  int off = offsets[e];

  extern __shared__ ushort smem[];           // 64 KiB: [A0][A1][B0][B1]
  ushort* ldsA = smem;
  ushort* ldsB = smem + 2 * ATILE;

  int tid = threadIdx.x;
  int lid = tid & 63, w = tid >> 6;
  int wm = w >> 1, wn = w & 1;               // 2x2 waves, per-wave 64x64
  int q = lid >> 4, l16 = lid & 15;
  int r0 = tid >> 3;                          // staging row in a 32-row unit
  int colElem = (((tid & 7) ^ (r0 & 7)) << 3);  // inverse-swizzled source col

  const ushort *aS[4], *bS[4];                // 4 units of 32 rows each
#pragma unroll
  for (int u = 0; u < 4; ++u) {
    int rA = min(m0 + u * 32 + r0, cnt - 1);
    int tok = IS_FC1 ? bucket_tok[e * CAP + rA] : (off + rA);
    aS[u] = Ab + (size_t)tok * KD + colElem;
    bS[u] = Bw + ((size_t)e * ND + n0 + u * 32 + r0) * KD + colElem;
  }

  f32x4 acc[4][4] = {};
  int nk = KD >> 6;

  auto STG = [&](int kt) {
    ushort* la = ldsA + ((kt & 1) ? ATILE : 0) + tid * 8;
    ushort* lb = ldsB + ((kt & 1) ? ATILE : 0) + tid * 8;
#pragma unroll
    for (int u = 0; u < 4; ++u) {
      gld16(aS[u] + kt * 64, la + u * 2048);
      gld16(bS[u] + kt * 64, lb + u * 2048);
    }
  };

  STG(0);
  __syncthreads();  // compiler inserts vmcnt(0) before s_barrier

  for (int kt = 0; kt < nk; ++kt) {
    if (kt + 1 < nk) STG(kt + 1);           // prefetch next tile (other buffer)
    const ushort* As = ldsA + ((kt & 1) ? ATILE : 0);
    const ushort* Bs = ldsB + ((kt & 1) ? ATILE : 0);
    short8 af[4][2], bfr[4][2];
#pragma unroll
    for (int mi = 0; mi < 4; ++mi)
#pragma unroll
      for (int ks = 0; ks < 2; ++ks)
        af[mi][ks] = ldsr(As, wm * 64 + mi * 16 + l16, ks, q);
#pragma unroll
    for (int nj = 0; nj < 4; ++nj)
#pragma unroll
      for (int ks = 0; ks < 2; ++ks)
        bfr[nj][ks] = ldsr(Bs, wn * 64 + nj * 16 + l16, ks, q);
#pragma unroll
    for (int mi = 0; mi < 4; ++mi)
#pragma unroll
      for (int nj = 0; nj < 4; ++nj)
#pragma unroll
        for (int ks = 0; ks < 2; ++ks)
          acc[mi][nj] = __builtin_amdgcn_mfma_f32_16x16x32_bf16(
              af[mi][ks], bfr[nj][ks], acc[mi][nj], 0, 0, 0);
    __syncthreads();  // single drain point: stage loads + all LDS reads done
  }

  // ---- epilogue via LDS round-trip (verified in 339us baseline, verbatim) ----
  float bcol[4];
#pragma unroll
  for (int j = 0; j < 4; ++j)
    bcol[j] = bias[(size_t)e * ND + n0 + wn * 64 + j * 16 + l16];

  if (IS_FC1) {
    ushort* Ct = smem;  // [32][136] bf16
#pragma unroll
    for (int i = 0; i < 4; i++) {
      __syncthreads();
#pragma unroll
      for (int j = 0; j < 4; j++)
#pragma unroll
        for (int r = 0; r < 4; r++) {
          float v = acc[i][j][r] + bcol[j];
          float g = 0.5f * v * (1.0f + erff(v * 0.70710678118654752f));
          Ct[(wm * 16 + q * 4 + r) * 136 + wn * 64 + j * 16 + l16] = f2bf(g);
        }
      __syncthreads();
#pragma unroll
      for (int u = 0; u < 2; u++) {
        int c = tid + u * 256;            // 512 chunks of 8 bf16
        int ml = c >> 4, cc = c & 15;
        int gm = m0 + (ml >> 4) * 64 + i * 16 + (ml & 15);
        if (gm < cnt)
          *(uint4*)&Aout[(size_t)(off + gm) * ND + n0 + cc * 8] =
              *(const uint4*)&Ct[ml * 136 + cc * 8];
      }
    }
  } else {
    float* Cf = (float*)smem;  // [32][132] fp32
#pragma unroll
    for (int i = 0; i < 4; i++) {
      __syncthreads();
#pragma unroll
      for (int r = 0; r < 4; r++) {
        int gm = m0 + wm * 64 + i * 16 + q * 4 + r;
        float wgt = bucket_w[e * CAP + min(gm, cnt - 1)];
#pragma unroll
        for (int j = 0; j < 4; j++)
          Cf[(wm * 16 + q * 4 + r) * 132 + wn * 64 + j * 16 + l16] = wgt * (acc[i][j][r] + bcol[j]);
      }
      __syncthreads();
#pragma unroll
      for (int u = 0; u < 4; u++) {
        int c = tid + u * 256;            // 1024 chunks of 4 floats
        int ml = c >> 5, cc = c & 31;
        int gm = m0 + (ml >> 4) * 64 + i * 16 + (ml & 15);
        if (gm < cnt)
          *(float4*)&Yout[(size_t)(off + gm) * ND + n0 + cc * 4] =
              *(const float4*)&Cf[ml * 132 + cc * 4];
      }
    }
  }
}

// ---------------- combine: out[t] = Y[row(e0,s0)] + Y[row(e1,s1)] ----------------
__global__ void combine_kernel(const float4* __restrict__ Y, const int4* __restrict__ tok_info,
                               const int* __restrict__ offsets, float4* __restrict__ out) {
  int t = blockIdx.x;
  int4 ti = tok_info[t];
  int g0 = offsets[ti.x] + ti.z;
  int g1 = offsets[ti.y] + ti.w;
  int i = threadIdx.x;  // 128 threads, H/4 = 128 float4 per row
  float4 a = Y[(size_t)g0 * (HD / 4) + i];
  float4 b = Y[(size_t)g1 * (HD / 4) + i];
  out[(size_t)t * (HD / 4) + i] = make_float4(a.x + b.x, a.y + b.y, a.z + b.z, a.w + b.w);
}

extern "C" void kernel_launch(void* const* d_in, const int* in_sizes, int n_in,
                              void* d_out, int out_size, void* d_ws, size_t ws_size,
                              hipStream_t stream) {
  const float* x    = (const float*)d_in[0];
  const float* rw   = (const float*)d_in[1];
  const float* fc1w = (const float*)d_in[2];
  const float* fc1b = (const float*)d_in[3];
  const float* fc2w = (const float*)d_in[4];
  const float* fc2b = (const float*)d_in[5];

  float* out   = (float*)d_out;
  float* probs = out + (size_t)T_TOKENS * HD;
  float* topk  = probs + (size_t)T_TOKENS * NE;

  static bool attr_done = false;
  if (!attr_done) {
    (void)hipFuncSetAttribute((const void*)&ffn_gemm_db<true>,
                              hipFuncAttributeMaxDynamicSharedMemorySize, 65536);
    (void)hipFuncSetAttribute((const void*)&ffn_gemm_db<false>,
                              hipFuncAttributeMaxDynamicSharedMemorySize, 65536);
    attr_done = true;
  }

  char* p = (char*)d_ws;
  auto carve = [&](size_t bytes) { char* r = p; p += (bytes + 255) & ~(size_t)255; return r; };
  int*    counts     = (int*)carve(NE * CSTRIDE * sizeof(int));
  int*    offsets    = (int*)carve(NE * sizeof(int));
  int*    bucket_tok = (int*)carve((size_t)NE * CAP * sizeof(int));
  float*  bucket_w   = (float*)carve((size_t)NE * CAP * sizeof(float));
  int4*   tok_info   = (int4*)carve((size_t)T_TOKENS * sizeof(int4));
  ushort* xb   = (ushort*)carve((size_t)T_TOKENS * HD * 2);
  ushort* w1b  = (ushort*)carve((size_t)NE * FD * HD * 2);
  ushort* w2b  = (ushort*)carve((size_t)NE * HD * FD * 2);
  ushort* Abuf = (ushort*)carve((size_t)T_TOKENS * 2 * FD * 2);  // compact GELU out, bf16
  float*  Y    = (float*)carve((size_t)T_TOKENS * 2 * HD * 4);   // gated FC2 rows, fp32

  hipMemsetAsync(counts, 0, NE * CSTRIDE * sizeof(int), stream);
  cvt_bf16<<<2048, 256, 0, stream>>>((const float4*)x, (ushort4*)xb, T_TOKENS * HD / 4);
  cvt_bf16<<<2048, 256, 0, stream>>>((const float4*)fc1w, (ushort4*)w1b, NE * FD * HD / 4);
  cvt_bf16<<<2048, 256, 0, stream>>>((const float4*)fc2w, (ushort4*)w2b, NE * HD * FD / 4);
  router_kernel<<<T_TOKENS / 64, 256, 0, stream>>>(x, rw, probs, topk, counts, bucket_tok,
                                                   bucket_w, tok_info);
  scan_kernel<<<1, 64, 0, stream>>>(counts, offsets);

  // FC1: 128x128 tile, K=512 (8 steps);  FC2: 128x128 tile, K=2048 (32 steps)
  ffn_gemm_db<true><<<dim3(FD / 128, CAP / 128, NE), 256, 65536, stream>>>(
      xb, w1b, fc1b, counts, offsets, bucket_tok, bucket_w, Abuf, nullptr, HD, FD);
  ffn_gemm_db<false><<<dim3(HD / 128, CAP / 128, NE), 256, 65536, stream>>>(
      Abuf, w2b, fc2b, counts, offsets, bucket_tok, bucket_w, nullptr, Y, FD, HD);

  combine_kernel<<<T_TOKENS, 128, 0, stream>>>((const float4*)Y, tok_info, offsets, (float4*)out);
}

// Round 7
// 314.263 us; speedup vs baseline: 1.1479x; 1.0636x over previous
//
#include <hip/hip_runtime.h>

// Problem constants: B=4, S=2048 -> T=8192 tokens; H=512, F=2048, E=8, K=2.
#define T_TOKENS 8192
#define HD 512
#define FD 2048
#define NE 8
#define CAP 8192   // per-expert bucket capacity (worst case all tokens -> one expert)
#define CSTRIDE 32 // counter padding: 32 ints = 128B, one counter per cache line

typedef __attribute__((ext_vector_type(8))) short short8;   // 8 bf16 = 4 VGPRs
typedef __attribute__((ext_vector_type(4))) float f32x4;    // MFMA accumulator

__device__ __forceinline__ ushort f2bf(float f) {
  union { float f; unsigned u; } v; v.f = f;
  unsigned u = v.u;
  return (ushort)((u + 0x7fffu + ((u >> 16) & 1u)) >> 16);  // RNE
}

// async global->LDS, 16B per lane. LDS dest is wave-uniform base + lane*16.
__device__ __forceinline__ void gld16(const ushort* g, ushort* l) {
  __builtin_amdgcn_global_load_lds(
      (const __attribute__((address_space(1))) void*)g,
      (__attribute__((address_space(3))) void*)l, 16, 0, 0);
}

// ---------------- fp32 -> bf16 bulk convert (3 arrays, one launch) -----------
__global__ void cvt_bf16_3(const float4* __restrict__ s0, ushort4* __restrict__ d0, int c0,
                           const float4* __restrict__ s1, ushort4* __restrict__ d1, int c1,
                           const float4* __restrict__ s2, ushort4* __restrict__ d2, int c2) {
  int i = blockIdx.x * blockDim.x + threadIdx.x;
  int st = gridDim.x * blockDim.x;
  int nt = c0 + c1 + c2;
  for (; i < nt; i += st) {
    const float4* s; ushort4* d; int j = i;
    if (j < c0) { s = s0; d = d0; }
    else if ((j -= c0) < c1) { s = s1; d = d1; }
    else { j -= c1; s = s2; d = d2; }
    float4 v = s[j];
    ushort4 o;
    o.x = f2bf(v.x); o.y = f2bf(v.y); o.z = f2bf(v.z); o.w = f2bf(v.w);
    d[j] = o;
  }
}

// ---------------- router: logits -> softmax -> top2 -> buckets ----------------
#define TPW 16
__global__ void router_kernel(const float* __restrict__ x, const float* __restrict__ rw,
                              float* __restrict__ probs_out, float* __restrict__ topk_out,
                              int* __restrict__ counts, int* __restrict__ bucket_tok,
                              float* __restrict__ bucket_w, int4* __restrict__ tok_info) {
  __shared__ int lcnt[NE];
  __shared__ int lbase[NE];
  __shared__ int ls_e0[64], ls_e1[64], ls_s0[64], ls_s1[64];
  __shared__ float ls_w0[64], ls_w1[64];

  int wave = threadIdx.x >> 6, lane = threadIdx.x & 63;
  if (threadIdx.x < NE) lcnt[threadIdx.x] = 0;
  __syncthreads();

  int tbase = blockIdx.x * 64;
  for (int it = 0; it < TPW; it++) {
    int lt = wave * TPW + it;
    int t = tbase + lt;
    float acc[NE];
#pragma unroll
    for (int e = 0; e < NE; e++) acc[e] = 0.f;
    const float* xr = x + (size_t)t * HD;
    for (int c = 0; c < HD; c += 64) {
      float xv = xr[c + lane];
#pragma unroll
      for (int e = 0; e < NE; e++) acc[e] += xv * rw[e * HD + c + lane];
    }
#pragma unroll
    for (int e = 0; e < NE; e++) {
#pragma unroll
      for (int s = 32; s > 0; s >>= 1) acc[e] += __shfl_xor(acc[e], s, 64);
    }
    if (lane == 0) {
      float m = acc[0];
#pragma unroll
      for (int e = 1; e < NE; e++) m = fmaxf(m, acc[e]);
      float p[NE], s = 0.f;
#pragma unroll
      for (int e = 0; e < NE; e++) { p[e] = expf(acc[e] - m); s += p[e]; }
      float inv = 1.f / s;
#pragma unroll
      for (int e = 0; e < NE; e++) { p[e] *= inv; probs_out[(size_t)t * NE + e] = p[e]; }
      int i0 = 0;
#pragma unroll
      for (int e = 1; e < NE; e++) if (p[e] > p[i0]) i0 = e;
      int i1 = (i0 == 0) ? 1 : 0;
#pragma unroll
      for (int e = 0; e < NE; e++) if (e != i0 && p[e] > p[i1]) i1 = e;
      float r = 1.f / (p[i0] + p[i1] + 1e-9f);
      topk_out[(size_t)t * 2 + 0] = (float)i0;
      topk_out[(size_t)t * 2 + 1] = (float)i1;
      ls_e0[lt] = i0; ls_e1[lt] = i1;
      ls_w0[lt] = p[i0] * r; ls_w1[lt] = p[i1] * r;
      ls_s0[lt] = atomicAdd(&lcnt[i0], 1);
      ls_s1[lt] = atomicAdd(&lcnt[i1], 1);
    }
  }
  __syncthreads();
  if (threadIdx.x < NE)
    lbase[threadIdx.x] = atomicAdd(&counts[threadIdx.x * CSTRIDE], lcnt[threadIdx.x]);
  __syncthreads();
  if (threadIdx.x < 64) {
    int lt = threadIdx.x, t = tbase + lt;
    int e0 = ls_e0[lt], e1 = ls_e1[lt];
    int g0 = lbase[e0] + ls_s0[lt];
    int g1 = lbase[e1] + ls_s1[lt];
    bucket_tok[e0 * CAP + g0] = t; bucket_w[e0 * CAP + g0] = ls_w0[lt];
    bucket_tok[e1 * CAP + g1] = t; bucket_w[e1 * CAP + g1] = ls_w1[lt];
    tok_info[t] = make_int4(e0, e1, g0, g1);
  }
}

__global__ void scan_kernel(const int* __restrict__ counts, int* __restrict__ offsets) {
  if (threadIdx.x == 0) {
    int o = 0;
#pragma unroll
    for (int e = 0; e < NE; e++) { offsets[e] = o; o += counts[e * CSTRIDE]; }
  }
}

// ---------------- 3-stage pipelined grouped GEMM (128x128, BK=32) -------------
// Theory (R5 counters): per-step vmcnt(0) drain + 2 blocks/CU = latency-bound
// (MfmaUtil 15%). Fix: 3 LDS buffers (48 KiB -> 3 blocks/CU) + counted
// vmcnt(8) in steady state (in-flight window = 2 compute steps), never 0
// until the tail. Two raw s_barriers per step:
//   STG(k+2 -> buf (k+2)%3); vmcnt(8); bar; ds_read buf k; lgkmcnt(0);
//   MFMA; bar.
// WAR-free: stage target (k+2)%3 is neither the read buffer k%3 nor (k+1)%3;
// its previous reader (tile k-1) retired reads before the prior exit barrier.
// BK=32 swizzle (derived, both-sides): read byte ^= ((row>>1)&3)<<4
// (16 lanes @ stride 64B -> 8 distinct 4-bank groups, 2 lanes each = free);
// staging keeps LDS dest linear, global source column = (tid&3)^((r0>>1)&3).

__device__ __forceinline__ short8 ldsr32(const ushort* base, int row, int q) {
  int a = row * 64 + q * 16;
  a ^= ((row >> 1) & 3) << 4;
  return *(const short8*)((const char*)base + a);
}

#define VMC(N) asm volatile("s_waitcnt vmcnt(" #N ")" ::: "memory")
#define SB0 __builtin_amdgcn_sched_barrier(0)

#define STG3(KT, SB_) do { \
    ushort* _la = bufA + (SB_) * TU + tid * 8; \
    ushort* _lb = bufB + (SB_) * TU + tid * 8; \
    gld16(aS0 + (KT) * 32, _la); gld16(aS1 + (KT) * 32, _la + 2048); \
    gld16(bS0 + (KT) * 32, _lb); gld16(bS1 + (KT) * 32, _lb + 2048); \
  } while (0)

#define CMP3(RB_) do { \
    const ushort* _As = bufA + (RB_) * TU; \
    const ushort* _Bs = bufB + (RB_) * TU; \
    short8 af[4], bfr[4]; \
    _Pragma("unroll") for (int mi = 0; mi < 4; ++mi) \
      af[mi] = ldsr32(_As, wm * 64 + mi * 16 + l16, q); \
    _Pragma("unroll") for (int nj = 0; nj < 4; ++nj) \
      bfr[nj] = ldsr32(_Bs, wn * 64 + nj * 16 + l16, q); \
    asm volatile("s_waitcnt lgkmcnt(0)" ::: "memory"); SB0; \
    __builtin_amdgcn_s_setprio(1); \
    _Pragma("unroll") for (int mi = 0; mi < 4; ++mi) \
      _Pragma("unroll") for (int nj = 0; nj < 4; ++nj) \
        acc[mi][nj] = __builtin_amdgcn_mfma_f32_16x16x32_bf16(af[mi], bfr[nj], acc[mi][nj], 0, 0, 0); \
    __builtin_amdgcn_s_setprio(0); \
  } while (0)

template <bool IS_FC1>
__global__ __launch_bounds__(256, 3)
void ffn_gemm_p3(const ushort* __restrict__ Ab, const ushort* __restrict__ Bw,
                 const float* __restrict__ bias, const int* __restrict__ counts,
                 const int* __restrict__ offsets, const int* __restrict__ bucket_tok,
                 const float* __restrict__ bucket_w, ushort* __restrict__ Aout,
                 float* __restrict__ Yout, int KD, int ND) {
  constexpr int TU = 128 * 32;   // ushorts per buffer (8 KB)

  int e = blockIdx.z;
  int cnt = counts[e * CSTRIDE];
  int m0 = blockIdx.y * 128;
  if (m0 >= cnt) return;
  int n0 = blockIdx.x * 128;
  int off = offsets[e];

  extern __shared__ ushort smem[];   // 48 KiB: A0 A1 A2 B0 B1 B2
  ushort* bufA = smem;
  ushort* bufB = smem + 3 * TU;

  int tid = threadIdx.x;
  int lid = tid & 63, w = tid >> 6;
  int wm = w >> 1, wn = w & 1;                 // 2x2 waves, per-wave 64x64
  int q = lid >> 4, l16 = lid & 15;
  int r0 = tid >> 2;                           // staging row 0..63 (4 lanes/row)
  int colElem = (((tid & 3) ^ ((r0 >> 1) & 3)) << 3);  // inverse-swizzled col

  const ushort *aS0, *aS1, *bS0, *bS1;
  {
    int rA0 = min(m0 + r0, cnt - 1);
    int rA1 = min(m0 + 64 + r0, cnt - 1);
    int t0 = IS_FC1 ? bucket_tok[e * CAP + rA0] : (off + rA0);
    int t1 = IS_FC1 ? bucket_tok[e * CAP + rA1] : (off + rA1);
    aS0 = Ab + (size_t)t0 * KD + colElem;
    aS1 = Ab + (size_t)t1 * KD + colElem;
    bS0 = Bw + ((size_t)e * ND + n0 + r0) * KD + colElem;
    bS1 = Bw + ((size_t)e * ND + n0 + 64 + r0) * KD + colElem;
  }

  f32x4 acc[4][4] = {};
  int nk = KD >> 5;   // BK=32; FC1: 16, FC2: 64 (both >= 3)

  STG3(0, 0); STG3(1, 1);
  int rb = 0, sb = 2;
  for (int k = 0; k < nk - 2; ++k) {
    STG3(k + 2, sb); SB0;
    VMC(8); SB0;                       // tile k fully resident (own loads)
    __builtin_amdgcn_s_barrier(); SB0; // all waves' tile-k loads in LDS
    CMP3(rb);
    SB0; __builtin_amdgcn_s_barrier(); // all waves' reads retired -> buf free
    rb = (rb == 2) ? 0 : rb + 1;
    sb = (sb == 2) ? 0 : sb + 1;
  }
  VMC(4); SB0; __builtin_amdgcn_s_barrier(); SB0;
  CMP3(rb); SB0; __builtin_amdgcn_s_barrier();
  rb = (rb == 2) ? 0 : rb + 1;
  VMC(0); SB0; __builtin_amdgcn_s_barrier(); SB0;
  CMP3(rb); SB0; __builtin_amdgcn_s_barrier();

  // ---- epilogue via LDS round-trip (verified R4/R5, verbatim) ----
  float bcol[4];
#pragma unroll
  for (int j = 0; j < 4; ++j)
    bcol[j] = bias[(size_t)e * ND + n0 + wn * 64 + j * 16 + l16];

  if (IS_FC1) {
    ushort* Ct = smem;  // [32][136] bf16
#pragma unroll
    for (int i = 0; i < 4; i++) {
      __syncthreads();
#pragma unroll
      for (int j = 0; j < 4; j++)
#pragma unroll
        for (int r = 0; r < 4; r++) {
          float v = acc[i][j][r] + bcol[j];
          float g = 0.5f * v * (1.0f + erff(v * 0.70710678118654752f));
          Ct[(wm * 16 + q * 4 + r) * 136 + wn * 64 + j * 16 + l16] = f2bf(g);
        }
      __syncthreads();
#pragma unroll
      for (int u = 0; u < 2; u++) {
        int c = tid + u * 256;            // 512 chunks of 8 bf16
        int ml = c >> 4, cc = c & 15;
        int gm = m0 + (ml >> 4) * 64 + i * 16 + (ml & 15);
        if (gm < cnt)
          *(uint4*)&Aout[(size_t)(off + gm) * ND + n0 + cc * 8] =
              *(const uint4*)&Ct[ml * 136 + cc * 8];
      }
    }
  } else {
    float* Cf = (float*)smem;  // [32][132] fp32
#pragma unroll
    for (int i = 0; i < 4; i++) {
      __syncthreads();
#pragma unroll
      for (int r = 0; r < 4; r++) {
        int gm = m0 + wm * 64 + i * 16 + q * 4 + r;
        float wgt = bucket_w[e * CAP + min(gm, cnt - 1)];
#pragma unroll
        for (int j = 0; j < 4; j++)
          Cf[(wm * 16 + q * 4 + r) * 132 + wn * 64 + j * 16 + l16] = wgt * (acc[i][j][r] + bcol[j]);
      }
      __syncthreads();
#pragma unroll
      for (int u = 0; u < 4; u++) {
        int c = tid + u * 256;            // 1024 chunks of 4 floats
        int ml = c >> 5, cc = c & 31;
        int gm = m0 + (ml >> 4) * 64 + i * 16 + (ml & 15);
        if (gm < cnt)
          *(float4*)&Yout[(size_t)(off + gm) * ND + n0 + cc * 4] =
              *(const float4*)&Cf[ml * 132 + cc * 4];
      }
    }
  }
}

// ---------------- combine: out[t] = Y[row(e0,s0)] + Y[row(e1,s1)] ----------------
__global__ void combine_kernel(const float4* __restrict__ Y, const int4* __restrict__ tok_info,
                               const int* __restrict__ offsets, float4* __restrict__ out) {
  int t = blockIdx.x;
  int4 ti = tok_info[t];
  int g0 = offsets[ti.x] + ti.z;
  int g1 = offsets[ti.y] + ti.w;
  int i = threadIdx.x;  // 128 threads, H/4 = 128 float4 per row
  float4 a = Y[(size_t)g0 * (HD / 4) + i];
  float4 b = Y[(size_t)g1 * (HD / 4) + i];
  out[(size_t)t * (HD / 4) + i] = make_float4(a.x + b.x, a.y + b.y, a.z + b.z, a.w + b.w);
}

extern "C" void kernel_launch(void* const* d_in, const int* in_sizes, int n_in,
                              void* d_out, int out_size, void* d_ws, size_t ws_size,
                              hipStream_t stream) {
  const float* x    = (const float*)d_in[0];
  const float* rw   = (const float*)d_in[1];
  const float* fc1w = (const float*)d_in[2];
  const float* fc1b = (const float*)d_in[3];
  const float* fc2w = (const float*)d_in[4];
  const float* fc2b = (const float*)d_in[5];

  float* out   = (float*)d_out;
  float* probs = out + (size_t)T_TOKENS * HD;
  float* topk  = probs + (size_t)T_TOKENS * NE;

  static bool attr_done = false;
  if (!attr_done) {
    (void)hipFuncSetAttribute((const void*)&ffn_gemm_p3<true>,
                              hipFuncAttributeMaxDynamicSharedMemorySize, 49152);
    (void)hipFuncSetAttribute((const void*)&ffn_gemm_p3<false>,
                              hipFuncAttributeMaxDynamicSharedMemorySize, 49152);
    attr_done = true;
  }

  char* p = (char*)d_ws;
  auto carve = [&](size_t bytes) { char* r = p; p += (bytes + 255) & ~(size_t)255; return r; };
  int*    counts     = (int*)carve(NE * CSTRIDE * sizeof(int));
  int*    offsets    = (int*)carve(NE * sizeof(int));
  int*    bucket_tok = (int*)carve((size_t)NE * CAP * sizeof(int));
  float*  bucket_w   = (float*)carve((size_t)NE * CAP * sizeof(float));
  int4*   tok_info   = (int4*)carve((size_t)T_TOKENS * sizeof(int4));
  ushort* xb   = (ushort*)carve((size_t)T_TOKENS * HD * 2);
  ushort* w1b  = (ushort*)carve((size_t)NE * FD * HD * 2);
  ushort* w2b  = (ushort*)carve((size_t)NE * HD * FD * 2);
  ushort* Abuf = (ushort*)carve((size_t)T_TOKENS * 2 * FD * 2);  // compact GELU out, bf16
  float*  Y    = (float*)carve((size_t)T_TOKENS * 2 * HD * 4);   // gated FC2 rows, fp32

  hipMemsetAsync(counts, 0, NE * CSTRIDE * sizeof(int), stream);
  cvt_bf16_3<<<4096, 256, 0, stream>>>(
      (const float4*)x,    (ushort4*)xb,  T_TOKENS * HD / 4,
      (const float4*)fc1w, (ushort4*)w1b, NE * FD * HD / 4,
      (const float4*)fc2w, (ushort4*)w2b, NE * HD * FD / 4);
  router_kernel<<<T_TOKENS / 64, 256, 0, stream>>>(x, rw, probs, topk, counts, bucket_tok,
                                                   bucket_w, tok_info);
  scan_kernel<<<1, 64, 0, stream>>>(counts, offsets);

  // FC1: K=512 (nk=16);  FC2: K=2048 (nk=64). 48 KiB LDS -> 3 blocks/CU.
  ffn_gemm_p3<true><<<dim3(FD / 128, CAP / 128, NE), 256, 49152, stream>>>(
      xb, w1b, fc1b, counts, offsets, bucket_tok, bucket_w, Abuf, nullptr, HD, FD);
  ffn_gemm_p3<false><<<dim3(HD / 128, CAP / 128, NE), 256, 49152, stream>>>(
      Abuf, w2b, fc2b, counts, offsets, bucket_tok, bucket_w, nullptr, Y, FD, HD);

  combine_kernel<<<T_TOKENS, 128, 0, stream>>>((const float4*)Y, tok_info, offsets, (float4*)out);
}

// Round 8
// 298.117 us; speedup vs baseline: 1.2101x; 1.0542x over previous
//
#include <hip/hip_runtime.h>

// Problem constants: B=4, S=2048 -> T=8192 tokens; H=512, F=2048, E=8, K=2.
#define T_TOKENS 8192
#define HD 512
#define FD 2048
#define NE 8
#define CAP 8192   // per-expert bucket capacity (worst case all tokens -> one expert)
#define CSTRIDE 32 // counter padding: 32 ints = 128B, one counter per cache line

typedef __attribute__((ext_vector_type(8))) short short8;   // 8 bf16 = 4 VGPRs
typedef __attribute__((ext_vector_type(4))) float f32x4;    // MFMA accumulator

__device__ __forceinline__ ushort f2bf(float f) {
  union { float f; unsigned u; } v; v.f = f;
  unsigned u = v.u;
  return (ushort)((u + 0x7fffu + ((u >> 16) & 1u)) >> 16);  // RNE
}

// async global->LDS, 16B per lane. LDS dest is wave-uniform base + lane*16.
__device__ __forceinline__ void gld16(const ushort* g, ushort* l) {
  __builtin_amdgcn_global_load_lds(
      (const __attribute__((address_space(1))) void*)g,
      (__attribute__((address_space(3))) void*)l, 16, 0, 0);
}

// Fast exact-erf GELU: Abramowitz-Stegun 7.1.26, |erf err| <= 1.5e-7 (exact exp);
// v_rcp_f32 (~1e-6 rel) + __expf keep total error ~1e-6 -- far below bf16 ulp.
__device__ __forceinline__ float gelu_fast(float v) {
  float u = v * 0.70710678118654752f;
  float x = fabsf(u);
  float d = __builtin_fmaf(0.3275911f, x, 1.0f);
  float t;
  asm("v_rcp_f32 %0, %1" : "=v"(t) : "v"(d));
  float y = t * (0.254829592f + t * (-0.284496736f +
            t * (1.421413741f + t * (-1.453152027f + t * 1.061405429f))));
  float erfabs = __builtin_fmaf(-y, __expf(-x * x), 1.0f);
  float erfv = copysignf(erfabs, u);
  return 0.5f * v * (1.0f + erfv);
}

// ---------------- fp32 -> bf16 bulk convert (weights only; x done in router) ---
__global__ void cvt_bf16_2(const float4* __restrict__ s0, ushort4* __restrict__ d0, int c0,
                           const float4* __restrict__ s1, ushort4* __restrict__ d1, int c1) {
  int i = blockIdx.x * blockDim.x + threadIdx.x;
  int st = gridDim.x * blockDim.x;
  int nt = c0 + c1;
  for (; i < nt; i += st) {
    const float4* s; ushort4* d; int j = i;
    if (j < c0) { s = s0; d = d0; }
    else { j -= c0; s = s1; d = d1; }
    float4 v = s[j];
    ushort4 o;
    o.x = f2bf(v.x); o.y = f2bf(v.y); o.z = f2bf(v.z); o.w = f2bf(v.w);
    d[j] = o;
  }
}

// ---------------- router: logits -> softmax -> top2 -> buckets (+ x -> bf16) ---
#define TPW 16
__global__ void router_kernel(const float* __restrict__ x, const float* __restrict__ rw,
                              float* __restrict__ probs_out, float* __restrict__ topk_out,
                              int* __restrict__ counts, int* __restrict__ bucket_tok,
                              float* __restrict__ bucket_w, int4* __restrict__ tok_info,
                              ushort* __restrict__ xb) {
  __shared__ int lcnt[NE];
  __shared__ int lbase[NE];
  __shared__ int ls_e0[64], ls_e1[64], ls_s0[64], ls_s1[64];
  __shared__ float ls_w0[64], ls_w1[64];

  int wave = threadIdx.x >> 6, lane = threadIdx.x & 63;
  if (threadIdx.x < NE) lcnt[threadIdx.x] = 0;
  __syncthreads();

  int tbase = blockIdx.x * 64;
  for (int it = 0; it < TPW; it++) {
    int lt = wave * TPW + it;
    int t = tbase + lt;
    float acc[NE];
#pragma unroll
    for (int e = 0; e < NE; e++) acc[e] = 0.f;
    const float* xr = x + (size_t)t * HD;
    ushort* xbr = xb + (size_t)t * HD;
    for (int c = 0; c < HD; c += 64) {
      float xv = xr[c + lane];
      xbr[c + lane] = f2bf(xv);   // bf16 conversion rides the router's read
#pragma unroll
      for (int e = 0; e < NE; e++) acc[e] += xv * rw[e * HD + c + lane];
    }
#pragma unroll
    for (int e = 0; e < NE; e++) {
#pragma unroll
      for (int s = 32; s > 0; s >>= 1) acc[e] += __shfl_xor(acc[e], s, 64);
    }
    if (lane == 0) {
      float m = acc[0];
#pragma unroll
      for (int e = 1; e < NE; e++) m = fmaxf(m, acc[e]);
      float p[NE], s = 0.f;
#pragma unroll
      for (int e = 0; e < NE; e++) { p[e] = expf(acc[e] - m); s += p[e]; }
      float inv = 1.f / s;
#pragma unroll
      for (int e = 0; e < NE; e++) { p[e] *= inv; probs_out[(size_t)t * NE + e] = p[e]; }
      int i0 = 0;
#pragma unroll
      for (int e = 1; e < NE; e++) if (p[e] > p[i0]) i0 = e;
      int i1 = (i0 == 0) ? 1 : 0;
#pragma unroll
      for (int e = 0; e < NE; e++) if (e != i0 && p[e] > p[i1]) i1 = e;
      float r = 1.f / (p[i0] + p[i1] + 1e-9f);
      topk_out[(size_t)t * 2 + 0] = (float)i0;
      topk_out[(size_t)t * 2 + 1] = (float)i1;
      ls_e0[lt] = i0; ls_e1[lt] = i1;
      ls_w0[lt] = p[i0] * r; ls_w1[lt] = p[i1] * r;
      ls_s0[lt] = atomicAdd(&lcnt[i0], 1);
      ls_s1[lt] = atomicAdd(&lcnt[i1], 1);
    }
  }
  __syncthreads();
  if (threadIdx.x < NE)
    lbase[threadIdx.x] = atomicAdd(&counts[threadIdx.x * CSTRIDE], lcnt[threadIdx.x]);
  __syncthreads();
  if (threadIdx.x < 64) {
    int lt = threadIdx.x, t = tbase + lt;
    int e0 = ls_e0[lt], e1 = ls_e1[lt];
    int g0 = lbase[e0] + ls_s0[lt];
    int g1 = lbase[e1] + ls_s1[lt];
    bucket_tok[e0 * CAP + g0] = t; bucket_w[e0 * CAP + g0] = ls_w0[lt];
    bucket_tok[e1 * CAP + g1] = t; bucket_w[e1 * CAP + g1] = ls_w1[lt];
    tok_info[t] = make_int4(e0, e1, g0, g1);
  }
}

__global__ void scan_kernel(const int* __restrict__ counts, int* __restrict__ offsets) {
  if (threadIdx.x == 0) {
    int o = 0;
#pragma unroll
    for (int e = 0; e < NE; e++) { offsets[e] = o; o += counts[e * CSTRIDE]; }
  }
}

// ---------------- 3-stage pipelined grouped GEMM (128x128, BK=32) -------------
// Schedule identical to the R7 HW-verified kernel (3 buffers, counted vmcnt(8),
// 2 s_barriers/step). R8 change: KD/ND are template params and the K-loop is
// FULLY UNROLLED -> buffer indices (k%3) are compile-time, so LDS addresses
// become base + imm `offset:` and global offsets fold into the load imm.
// This removes the per-step VALU address recomputation (R7: VALUBusy 50%).

__device__ __forceinline__ short8 ldsr32(const ushort* base, int row, int q) {
  int a = row * 64 + q * 16;
  a ^= ((row >> 1) & 3) << 4;
  return *(const short8*)((const char*)base + a);
}

#define VMC(N) asm volatile("s_waitcnt vmcnt(" #N ")" ::: "memory")
#define SB0 __builtin_amdgcn_sched_barrier(0)

#define STG3(KT, SB_) do { \
    ushort* _la = bufA + (SB_) * TU + tid * 8; \
    ushort* _lb = bufB + (SB_) * TU + tid * 8; \
    gld16(aS0 + (KT) * 32, _la); gld16(aS1 + (KT) * 32, _la + 2048); \
    gld16(bS0 + (KT) * 32, _lb); gld16(bS1 + (KT) * 32, _lb + 2048); \
  } while (0)

#define CMP3(RB_) do { \
    const ushort* _As = bufA + (RB_) * TU; \
    const ushort* _Bs = bufB + (RB_) * TU; \
    short8 af[4], bfr[4]; \
    _Pragma("unroll") for (int mi = 0; mi < 4; ++mi) \
      af[mi] = ldsr32(_As, wm * 64 + mi * 16 + l16, q); \
    _Pragma("unroll") for (int nj = 0; nj < 4; ++nj) \
      bfr[nj] = ldsr32(_Bs, wn * 64 + nj * 16 + l16, q); \
    asm volatile("s_waitcnt lgkmcnt(0)" ::: "memory"); SB0; \
    __builtin_amdgcn_s_setprio(1); \
    _Pragma("unroll") for (int mi = 0; mi < 4; ++mi) \
      _Pragma("unroll") for (int nj = 0; nj < 4; ++nj) \
        acc[mi][nj] = __builtin_amdgcn_mfma_f32_16x16x32_bf16(af[mi], bfr[nj], acc[mi][nj], 0, 0, 0); \
    __builtin_amdgcn_s_setprio(0); \
  } while (0)

template <bool IS_FC1, int KD_, int ND_>
__global__ __launch_bounds__(256, 3)
void ffn_gemm_p3(const ushort* __restrict__ Ab, const ushort* __restrict__ Bw,
                 const float* __restrict__ bias, const int* __restrict__ counts,
                 const int* __restrict__ offsets, const int* __restrict__ bucket_tok,
                 const float* __restrict__ bucket_w, ushort* __restrict__ Aout,
                 float* __restrict__ Yout) {
  constexpr int TU = 128 * 32;   // ushorts per buffer (8 KB)
  constexpr int NK = KD_ >> 5;   // FC1: 16, FC2: 64
  static_assert(NK >= 3, "pipeline needs >= 3 K-steps");

  int e = blockIdx.z;
  int cnt = counts[e * CSTRIDE];
  int m0 = blockIdx.y * 128;
  if (m0 >= cnt) return;
  int n0 = blockIdx.x * 128;
  int off = offsets[e];

  extern __shared__ ushort smem[];   // 48 KiB: A0 A1 A2 B0 B1 B2
  ushort* bufA = smem;
  ushort* bufB = smem + 3 * TU;

  int tid = threadIdx.x;
  int lid = tid & 63, w = tid >> 6;
  int wm = w >> 1, wn = w & 1;                 // 2x2 waves, per-wave 64x64
  int q = lid >> 4, l16 = lid & 15;
  int r0 = tid >> 2;                           // staging row 0..63 (4 lanes/row)
  int colElem = (((tid & 3) ^ ((r0 >> 1) & 3)) << 3);  // inverse-swizzled col

  const ushort *aS0, *aS1, *bS0, *bS1;
  {
    int rA0 = min(m0 + r0, cnt - 1);
    int rA1 = min(m0 + 64 + r0, cnt - 1);
    int t0 = IS_FC1 ? bucket_tok[e * CAP + rA0] : (off + rA0);
    int t1 = IS_FC1 ? bucket_tok[e * CAP + rA1] : (off + rA1);
    aS0 = Ab + (size_t)t0 * KD_ + colElem;
    aS1 = Ab + (size_t)t1 * KD_ + colElem;
    bS0 = Bw + ((size_t)e * ND_ + n0 + r0) * KD_ + colElem;
    bS1 = Bw + ((size_t)e * ND_ + n0 + 64 + r0) * KD_ + colElem;
  }

  f32x4 acc[4][4] = {};

  STG3(0, 0); STG3(1, 1);
#pragma unroll
  for (int k = 0; k < NK - 2; ++k) {
    STG3(k + 2, (k + 2) % 3); SB0;
    VMC(8); SB0;                       // tile k fully resident (own loads)
    __builtin_amdgcn_s_barrier(); SB0; // all waves' tile-k loads in LDS
    CMP3(k % 3);
    SB0; __builtin_amdgcn_s_barrier(); // all waves' reads retired -> buf free
  }
  VMC(4); SB0; __builtin_amdgcn_s_barrier(); SB0;
  CMP3((NK - 2) % 3); SB0; __builtin_amdgcn_s_barrier();
  VMC(0); SB0; __builtin_amdgcn_s_barrier(); SB0;
  CMP3((NK - 1) % 3); SB0; __builtin_amdgcn_s_barrier();

  // ---- epilogue via LDS round-trip (layout verified R4/R5/R7) ----
  float bcol[4];
#pragma unroll
  for (int j = 0; j < 4; ++j)
    bcol[j] = bias[(size_t)e * ND_ + n0 + wn * 64 + j * 16 + l16];

  if (IS_FC1) {
    ushort* Ct = smem;  // [32][136] bf16
#pragma unroll
    for (int i = 0; i < 4; i++) {
      __syncthreads();
#pragma unroll
      for (int j = 0; j < 4; j++)
#pragma unroll
        for (int r = 0; r < 4; r++) {
          float v = acc[i][j][r] + bcol[j];
          Ct[(wm * 16 + q * 4 + r) * 136 + wn * 64 + j * 16 + l16] = f2bf(gelu_fast(v));
        }
      __syncthreads();
#pragma unroll
      for (int u = 0; u < 2; u++) {
        int c = tid + u * 256;            // 512 chunks of 8 bf16
        int ml = c >> 4, cc = c & 15;
        int gm = m0 + (ml >> 4) * 64 + i * 16 + (ml & 15);
        if (gm < cnt)
          *(uint4*)&Aout[(size_t)(off + gm) * ND_ + n0 + cc * 8] =
              *(const uint4*)&Ct[ml * 136 + cc * 8];
      }
    }
  } else {
    float* Cf = (float*)smem;  // [32][132] fp32
#pragma unroll
    for (int i = 0; i < 4; i++) {
      __syncthreads();
#pragma unroll
      for (int r = 0; r < 4; r++) {
        int gm = m0 + wm * 64 + i * 16 + q * 4 + r;
        float wgt = bucket_w[e * CAP + min(gm, cnt - 1)];
#pragma unroll
        for (int j = 0; j < 4; j++)
          Cf[(wm * 16 + q * 4 + r) * 132 + wn * 64 + j * 16 + l16] = wgt * (acc[i][j][r] + bcol[j]);
      }
      __syncthreads();
#pragma unroll
      for (int u = 0; u < 4; u++) {
        int c = tid + u * 256;            // 1024 chunks of 4 floats
        int ml = c >> 5, cc = c & 31;
        int gm = m0 + (ml >> 4) * 64 + i * 16 + (ml & 15);
        if (gm < cnt)
          *(float4*)&Yout[(size_t)(off + gm) * ND_ + n0 + cc * 4] =
              *(const float4*)&Cf[ml * 132 + cc * 4];
      }
    }
  }
}

// ---------------- combine: out[t] = Y[row(e0,s0)] + Y[row(e1,s1)] ----------------
__global__ void combine_kernel(const float4* __restrict__ Y, const int4* __restrict__ tok_info,
                               const int* __restrict__ offsets, float4* __restrict__ out) {
  int t = blockIdx.x;
  int4 ti = tok_info[t];
  int g0 = offsets[ti.x] + ti.z;
  int g1 = offsets[ti.y] + ti.w;
  int i = threadIdx.x;  // 128 threads, H/4 = 128 float4 per row
  float4 a = Y[(size_t)g0 * (HD / 4) + i];
  float4 b = Y[(size_t)g1 * (HD / 4) + i];
  out[(size_t)t * (HD / 4) + i] = make_float4(a.x + b.x, a.y + b.y, a.z + b.z, a.w + b.w);
}

extern "C" void kernel_launch(void* const* d_in, const int* in_sizes, int n_in,
                              void* d_out, int out_size, void* d_ws, size_t ws_size,
                              hipStream_t stream) {
  const float* x    = (const float*)d_in[0];
  const float* rw   = (const float*)d_in[1];
  const float* fc1w = (const float*)d_in[2];
  const float* fc1b = (const float*)d_in[3];
  const float* fc2w = (const float*)d_in[4];
  const float* fc2b = (const float*)d_in[5];

  float* out   = (float*)d_out;
  float* probs = out + (size_t)T_TOKENS * HD;
  float* topk  = probs + (size_t)T_TOKENS * NE;

  static bool attr_done = false;
  if (!attr_done) {
    (void)hipFuncSetAttribute((const void*)&ffn_gemm_p3<true, HD, FD>,
                              hipFuncAttributeMaxDynamicSharedMemorySize, 49152);
    (void)hipFuncSetAttribute((const void*)&ffn_gemm_p3<false, FD, HD>,
                              hipFuncAttributeMaxDynamicSharedMemorySize, 49152);
    attr_done = true;
  }

  char* p = (char*)d_ws;
  auto carve = [&](size_t bytes) { char* r = p; p += (bytes + 255) & ~(size_t)255; return r; };
  int*    counts     = (int*)carve(NE * CSTRIDE * sizeof(int));
  int*    offsets    = (int*)carve(NE * sizeof(int));
  int*    bucket_tok = (int*)carve((size_t)NE * CAP * sizeof(int));
  float*  bucket_w   = (float*)carve((size_t)NE * CAP * sizeof(float));
  int4*   tok_info   = (int4*)carve((size_t)T_TOKENS * sizeof(int4));
  ushort* xb   = (ushort*)carve((size_t)T_TOKENS * HD * 2);
  ushort* w1b  = (ushort*)carve((size_t)NE * FD * HD * 2);
  ushort* w2b  = (ushort*)carve((size_t)NE * HD * FD * 2);
  ushort* Abuf = (ushort*)carve((size_t)T_TOKENS * 2 * FD * 2);  // compact GELU out, bf16
  float*  Y    = (float*)carve((size_t)T_TOKENS * 2 * HD * 4);   // gated FC2 rows, fp32

  hipMemsetAsync(counts, 0, NE * CSTRIDE * sizeof(int), stream);
  cvt_bf16_2<<<4096, 256, 0, stream>>>(
      (const float4*)fc1w, (ushort4*)w1b, NE * FD * HD / 4,
      (const float4*)fc2w, (ushort4*)w2b, NE * HD * FD / 4);
  router_kernel<<<T_TOKENS / 64, 256, 0, stream>>>(x, rw, probs, topk, counts, bucket_tok,
                                                   bucket_w, tok_info, xb);
  scan_kernel<<<1, 64, 0, stream>>>(counts, offsets);

  // FC1: K=512 (NK=16);  FC2: K=2048 (NK=64). 48 KiB LDS -> 3 blocks/CU.
  ffn_gemm_p3<true, HD, FD><<<dim3(FD / 128, CAP / 128, NE), 256, 49152, stream>>>(
      xb, w1b, fc1b, counts, offsets, bucket_tok, bucket_w, Abuf, nullptr);
  ffn_gemm_p3<false, FD, HD><<<dim3(HD / 128, CAP / 128, NE), 256, 49152, stream>>>(
      Abuf, w2b, fc2b, counts, offsets, bucket_tok, bucket_w, nullptr, Y);

  combine_kernel<<<T_TOKENS, 128, 0, stream>>>((const float4*)Y, tok_info, offsets, (float4*)out);
}